// Round 12
// baseline (434.506 us; speedup 1.0000x reference)
//
#include <hip/hip_runtime.h>
#include <stdint.h>

#define D_DIM 256
#define NPAD  640   // 256 (W_lin) + 256 (W_res) + 8 (att_l) + 8 (att_r) + 112 zero pad -> 5 x 128 tiles
#define NSH   8     // histogram shards (R9: marginal but harmless)

typedef __bf16 bf16x8 __attribute__((ext_vector_type(8)));
typedef float  f32x4  __attribute__((ext_vector_type(4)));

__device__ __forceinline__ float bf2f(unsigned short u) {
  union { unsigned int i; float f; } cv; cv.i = ((unsigned int)u) << 16; return cv.f;
}
__device__ __forceinline__ unsigned short f2bf(float f) {
  union { float f; unsigned int i; } cv; cv.f = f;
  unsigned int i = cv.i;
  unsigned int lsb = (i >> 16) & 1u;
  i += 0x7fffu + lsb;   // round-to-nearest-even
  return (unsigned short)(i >> 16);
}
__device__ __forceinline__ void gld16(const void* gptr, void* lptr) {
  __builtin_amdgcn_global_load_lds(
      (const __attribute__((address_space(1))) unsigned int*)gptr,
      (__attribute__((address_space(3))) unsigned int*)lptr, 16, 0, 0);
}

// ---------------- fused setup: [hist | cvt_feat | prep_bt] (R9-measured: 73.4 us) ----------------
// hist is return-value atomics (rank) -> latency-bound, ~73 us structural (R9 sharding
// falsified line-contention; R10/R11 showed it does NOT hide under MFMA). cvt/prep's
// streaming DOES ride under it for free (R8/R9: fused == hist alone).
__global__ __launch_bounds__(256) void setup_fused(
    const float* __restrict__ feat, unsigned short* __restrict__ fb,
    const float* __restrict__ W_lin, const float* __restrict__ W_res,
    const float* __restrict__ att_l, const float* __restrict__ att_r,
    unsigned short* __restrict__ Bt, int nelem, int nb_hist, int nb_cvt,
    const int* __restrict__ dst, int* __restrict__ cntS, int* __restrict__ rank,
    int E, int Np) {
  int bid = blockIdx.x, t = threadIdx.x;
  if (bid < nb_hist) {
    int base = bid * 2048 + t;
    #pragma unroll
    for (int u = 0; u < 8; ++u) {
      int e = base + u * 256;
      if (e < E) {
        int d = dst[e];
        rank[e] = atomicAdd(&cntS[(e & (NSH - 1)) * Np + d], 1);
      }
    }
    return;
  }
  bid -= nb_hist;
  if (bid < nb_cvt) {
    int i = (bid * 256 + t) * 8;
    if (i >= nelem) return;
    float4 v0 = *(const float4*)(feat + i);
    float4 v1 = *(const float4*)(feat + i + 4);
    ushort4 a, b;
    a.x = f2bf(v0.x); a.y = f2bf(v0.y); a.z = f2bf(v0.z); a.w = f2bf(v0.w);
    b.x = f2bf(v1.x); b.y = f2bf(v1.y); b.z = f2bf(v1.z); b.w = f2bf(v1.w);
    *(ushort4*)(fb + i) = a;
    *(ushort4*)(fb + i + 4) = b;
  } else {
    int idx = (bid - nb_cvt) * 256 + t;   // covers NPAD*D_DIM exactly
    int n = idx >> 8, k = idx & 255;
    float v = 0.f;
    if (n < 256) v = W_lin[k * 256 + n];
    else if (n < 512) v = W_res[k * 256 + (n - 256)];
    else if (n < 520) {
      int h = n - 512; float s = 0.f;
      #pragma unroll
      for (int c = 0; c < 32; ++c) s += W_lin[k * 256 + h * 32 + c] * att_l[h * 32 + c];
      v = s;
    } else if (n < 528) {
      int h = n - 520; float s = 0.f;
      #pragma unroll
      for (int c = 0; c < 32; ++c) s += W_lin[k * 256 + h * 32 + c] * att_r[h * 32 + c];
      v = s;
    }
    Bt[idx] = f2bf(v);
  }
}

// ---------------- scans (shard-aware; run BEFORE gemm so scatter can fuse into it) ----------------
__global__ __launch_bounds__(256) void scan_partial(const int* __restrict__ cntS,
                                                    int* __restrict__ bsum, int N, int Np) {
  __shared__ int s[256];
  int t = threadIdx.x;
  int i = blockIdx.x * 256 + t;
  int v = 0;
  if (i < N) {
    #pragma unroll
    for (int sh = 0; sh < NSH; ++sh) v += cntS[sh * Np + i];
  }
  s[t] = v;
  __syncthreads();
  for (int off = 128; off > 0; off >>= 1) {
    if (t < off) s[t] += s[t + off];
    __syncthreads();
  }
  if (t == 0) bsum[blockIdx.x] = s[0];
}

__global__ __launch_bounds__(256) void scan_apply(const int* __restrict__ cntS,
                                                  const int* __restrict__ bsum,
                                                  int* __restrict__ row_ptr,
                                                  int* __restrict__ soffA, int N, int Np) {
  __shared__ int red[256];
  __shared__ int s[256];
  int t = threadIdx.x;
  int b = blockIdx.x;
  int acc = 0;
  for (int j = t; j < b; j += 256) acc += bsum[j];
  red[t] = acc;
  __syncthreads();
  for (int off = 128; off > 0; off >>= 1) {
    if (t < off) red[t] += red[t + off];
    __syncthreads();
  }
  int base = red[0];

  int i = b * 256 + t;
  int c[NSH]; int v = 0;
  if (i < N) {
    #pragma unroll
    for (int sh = 0; sh < NSH; ++sh) { c[sh] = cntS[sh * Np + i]; v += c[sh]; }
  }
  s[t] = v;
  __syncthreads();
  for (int off = 1; off < 256; off <<= 1) {
    int u = (t >= off) ? s[t - off] : 0;
    __syncthreads();
    s[t] += u;
    __syncthreads();
  }
  int excl = base + s[t] - v;
  if (i < N) {
    row_ptr[i] = excl;
    int run = excl;
    #pragma unroll
    for (int sh = 0; sh < NSH; ++sh) { soffA[sh * Np + i] = run; run += c[sh]; }
    if (i == N - 1) row_ptr[N] = excl + v;
  }
}

// ---------------- fused [gemm | scatter] with interleaved role blocks ----------------
// Fusion ledger: hist (RETURN-value atomics) failed to overlap with GEMM three ways
// (R2 117, R10 146-serial, R11 ~140): waves stall in vmcnt on the RMW round trip.
// Scatter is the OPPOSITE traffic class: random 8 B stores with NO return value --
// waves issue and retire; the drain rides the TCC in the background under MFMA/LDS.
// Role blocks 1-per-6 (exact: gemm tiles = gx*5, scatter blocks = gx); scans already
// ran, so soffA/rank are ready. pairs must NOT alias fb here (gemm reads fb
// concurrently) -> fused path requires the separate pairs allocation; else fall back
// to split launches with the proven alias.
__global__ __launch_bounds__(256) void gemm_scatter(
    const unsigned short* __restrict__ A,   // feat bf16 [M][256]
    const unsigned short* __restrict__ Bt,  // [640][256]
    float* __restrict__ out, unsigned short* __restrict__ xbf,
    float* __restrict__ alpha_l, float* __restrict__ alpha_r, int M, int gx,
    const int* __restrict__ eidx, const float* __restrict__ ew,
    const int* __restrict__ soffA, const int* __restrict__ rank,
    int2* __restrict__ pairs, int E, int Np, int echunk, int fuse) {
  __shared__ unsigned short As[128 * 64];
  __shared__ unsigned short Bs[128 * 64];

  int tid  = threadIdx.x;
  int bid  = (int)blockIdx.x;
  int grp  = bid / 6, pos = bid - grp * 6;

  if (pos == 5) {
    // ---- scatter role: fire-and-forget stores, co-resident with gemm blocks ----
    if (!fuse) return;
    int ebase = grp * echunk;
    int elim  = ebase + echunk; if (elim > E) elim = E;
    for (int eb = ebase; eb < elim; eb += 2048) {
      #pragma unroll
      for (int u = 0; u < 8; ++u) {              // 8 independent edge streams in flight
        int e = eb + u * 256 + tid;
        if (e < elim) {
          int s = eidx[e], d = eidx[E + e];
          int p2 = soffA[(e & (NSH - 1)) * Np + d] + rank[e];
          int2 pr; pr.x = s; pr.y = __float_as_int(ew[e]);
          pairs[p2] = pr;
        }
      }
    }
    return;
  }

  int w    = tid >> 6, lane = tid & 63;
  int gb   = grp * 5 + pos;                       // gemm tile index in [0, gx*5)

  // bijective XCD-chunk swizzle over the gemm-tile space (ng = gx*5)
  int ng   = gx * 5;
  int q    = ng >> 3, r = ng & 7;
  int xcd  = gb & 7, j = gb >> 3;
  int wg   = (xcd < r ? xcd * (q + 1) : r * (q + 1) + (xcd - r) * q) + j;

  int nbn  = NPAD / 128;                   // 5
  int bm   = (wg / nbn) * 128, bn = (wg % nbn) * 128;   // bm-major: A-tile reuse
  int wm   = (w & 1) * 64, wn = (w >> 1) * 64;
  int l16  = lane & 15, quad = lane >> 4;

  f32x4 acc[4][4] = {};

  int sr8     = lane >> 3;                       // row within 8-row staging group
  int koff_sw = (((lane & 7) ^ sr8) * 8);        // pre-swizzled source column (elements)

  for (int k0 = 0; k0 < 256; k0 += 64) {
    #pragma unroll
    for (int jj = 0; jj < 4; ++jj) {
      int rbase = w * 32 + jj * 8;
      int rga = bm + rbase + sr8; if (rga > M - 1) rga = M - 1;   // clamp (stores guarded)
      gld16(A  + (size_t)rga * 256 + k0 + koff_sw, &As[rbase * 64]);
      gld16(Bt + (size_t)(bn + rbase + sr8) * 256 + k0 + koff_sw, &Bs[rbase * 64]);
    }
    __syncthreads();
    #pragma unroll
    for (int kk = 0; kk < 64; kk += 32) {
      bf16x8 a[4], b[4];
      #pragma unroll
      for (int mi = 0; mi < 4; ++mi) {
        int rr = wm + mi * 16 + l16;
        int col = (kk * 2 + quad * 16) ^ ((rr & 7) << 4);   // byte col, same involution
        a[mi] = *(const bf16x8*)((const char*)&As[rr * 64] + col);
      }
      #pragma unroll
      for (int ni = 0; ni < 4; ++ni) {
        int rr = wn + ni * 16 + l16;
        int col = (kk * 2 + quad * 16) ^ ((rr & 7) << 4);
        b[ni] = *(const bf16x8*)((const char*)&Bs[rr * 64] + col);
      }
      #pragma unroll
      for (int mi = 0; mi < 4; ++mi)
        #pragma unroll
        for (int ni = 0; ni < 4; ++ni)
          acc[mi][ni] = __builtin_amdgcn_mfma_f32_16x16x32_bf16(a[mi], b[ni], acc[mi][ni], 0, 0, 0);
    }
    __syncthreads();
  }

  #pragma unroll
  for (int mi = 0; mi < 4; ++mi) {
    #pragma unroll
    for (int rr = 0; rr < 4; ++rr) {
      int row = bm + wm + mi * 16 + quad * 4 + rr;
      if (row >= M) continue;
      #pragma unroll
      for (int ni = 0; ni < 4; ++ni) {
        int n = bn + wn + ni * 16 + l16;
        float v = acc[mi][ni][rr];
        if (n < 256)      xbf[(size_t)row * 256 + n] = f2bf(v);
        else if (n < 512) out[(size_t)row * 256 + (n - 256)] = v;
        else if (n < 520) alpha_l[row * 8 + (n - 512)] = v;
        else if (n < 528) alpha_r[row * 8 + (n - 520)] = v;
      }
    }
  }
}

// ---------------- standalone scatter (workspace fallback only) ----------------
__global__ __launch_bounds__(256) void scatter_kernel(
    const int* __restrict__ eidx, const float* __restrict__ ew,
    const int* __restrict__ soffA, const int* __restrict__ rank,
    int2* __restrict__ pairs, int E, int Np) {
  int e = blockIdx.x * 256 + threadIdx.x;
  if (e < E) {
    int d = eidx[E + e];
    int pos = soffA[(e & (NSH - 1)) * Np + d] + rank[e];
    int2 p; p.x = eidx[e]; p.y = __float_as_int(ew[e]);
    pairs[pos] = p;
  }
}

// ---------------- agg: 2 waves per dst node, alpha+exp in-loop (R3 form) ----------------
__global__ __launch_bounds__(256) void agg_kernel(
    const int* __restrict__ row_ptr, const int2* __restrict__ pairs,
    const float* __restrict__ alpha_l, const float* __restrict__ alpha_r,
    const unsigned short* __restrict__ xbf, float* __restrict__ out, int N) {
  __shared__ float red[2][64][6];        // [node-in-block][lane][l,ac0..3] (+pad)
  int nin  = threadIdx.x >> 7;           // node within block
  int wv   = (threadIdx.x >> 6) & 1;     // wave within node
  int lane = threadIdx.x & 63;
  int node = blockIdx.x * 2 + nin;
  bool active = node < N;
  int h  = lane >> 3;                    // head for this lane's 4 channels
  int cb = lane << 2;                    // channel base (0..252)

  float l = 0.f, ac0 = 0.f, ac1 = 0.f, ac2 = 0.f, ac3 = 0.f;

  if (active) {
    int beg = row_ptr[node], end = row_ptr[node + 1];
    if (beg < end) {
      float arv = alpha_r[node * 8 + h];
      int last = end - 1;
      const unsigned short* xb = xbf + cb;
      for (int jg = beg + wv * 4; jg < end; jg += 8) {
        int2 q[4];
        #pragma unroll
        for (int u = 0; u < 4; ++u) {
          int t = jg + u; t = (t < last) ? t : last;   // clamp (masked below)
          q[u] = pairs[t];
        }
        float al[4];
        #pragma unroll
        for (int u = 0; u < 4; ++u) al[u] = alpha_l[(size_t)q[u].x * 8 + h];
        ushort4 xv[4];
        #pragma unroll
        for (int u = 0; u < 4; ++u)
          xv[u] = *(const ushort4*)(xb + ((size_t)q[u].x << 8));
        #pragma unroll
        for (int u = 0; u < 4; ++u) {
          float a = __int_as_float(q[u].y) * (al[u] + arv);
          a = (a > 0.f) ? a : 0.2f * a;            // leaky_relu(0.2)
          float p = __expf(a);
          p = (jg + u < end) ? p : 0.f;            // mask tail
          l += p;
          ac0 = fmaf(p, bf2f(xv[u].x), ac0);
          ac1 = fmaf(p, bf2f(xv[u].y), ac1);
          ac2 = fmaf(p, bf2f(xv[u].z), ac2);
          ac3 = fmaf(p, bf2f(xv[u].w), ac3);
        }
      }
    }
  }

  if (wv == 1) {
    red[nin][lane][0] = l;
    red[nin][lane][1] = ac0; red[nin][lane][2] = ac1;
    red[nin][lane][3] = ac2; red[nin][lane][4] = ac3;
  }
  __syncthreads();
  if (active && wv == 0) {
    l   += red[nin][lane][0];
    ac0 += red[nin][lane][1]; ac1 += red[nin][lane][2];
    ac2 += red[nin][lane][3]; ac3 += red[nin][lane][4];
    float r = 1.0f / (l + 1e-16f);
    float o0 = ac0 * r, o1 = ac1 * r, o2 = ac2 * r, o3 = ac3 * r;
    o0 = (o0 > 0.f) ? o0 : expm1f(o0);  // elu
    o1 = (o1 > 0.f) ? o1 : expm1f(o1);
    o2 = (o2 > 0.f) ? o2 : expm1f(o2);
    o3 = (o3 > 0.f) ? o3 : expm1f(o3);
    float4* op = (float4*)(out + ((size_t)node << 8) + cb);
    float4 res = *op;                    // residual written by gemm epilogue
    res.x += o0; res.y += o1; res.z += o2; res.w += o3;
    *op = res;
  }
}

extern "C" void kernel_launch(void* const* d_in, const int* in_sizes, int n_in,
                              void* d_out, int out_size, void* d_ws, size_t ws_size,
                              hipStream_t stream) {
  const float* feat  = (const float*)d_in[0];
  const float* ew    = (const float*)d_in[1];
  const float* W_lin = (const float*)d_in[2];
  const float* att_l = (const float*)d_in[3];
  const float* att_r = (const float*)d_in[4];
  const float* W_res = (const float*)d_in[5];
  const int*   eidx  = (const int*)d_in[6];
  float* out = (float*)d_out;

  int N = in_sizes[0] / D_DIM;
  int E = in_sizes[1];
  int Np = (N + 255) & ~255;            // padded shard stride

  char* p = (char*)d_ws;
  auto alloc = [&](size_t bytes) {
    char* r = p; p += (bytes + 255) & ~(size_t)255; return r;
  };
  unsigned short* xbf  = (unsigned short*)alloc((size_t)N * 256 * 2);   // 25.6 MB
  unsigned short* fb   = (unsigned short*)alloc((size_t)N * 256 * 2);   // 25.6 MB
  float* alpha_l       = (float*)alloc((size_t)N * 8 * 4);
  float* alpha_r       = (float*)alloc((size_t)N * 8 * 4);
  unsigned short* Bt   = (unsigned short*)alloc((size_t)NPAD * D_DIM * 2);
  int*   row_ptr       = (int*)alloc((size_t)(N + 1) * 4);
  int*   cntS          = (int*)alloc((size_t)NSH * Np * 4);             // 1.6 MB
  int*   soffA         = (int*)alloc((size_t)NSH * Np * 4);             // 1.6 MB
  int*   rank          = (int*)alloc((size_t)E * 4);
  int*   bsum          = (int*)alloc(1024);
  int2*  pairs_sep     = (int2*)alloc((size_t)E * 8);                   // 12.8 MB
  bool sep_ok = ((size_t)((char*)(pairs_sep + E) - (char*)d_ws) <= ws_size);
  // fused gemm|scatter requires pairs disjoint from fb (gemm reads fb concurrently).
  // Fallback: pairs aliases fb and scatter runs as a separate kernel after gemm.
  int2* pairs = sep_ok ? pairs_sep : (int2*)fb;
  int fuse = sep_ok ? 1 : 0;

  int nb      = (N + 255) / 256;
  int nb_cvt  = (N * 256 / 8 + 255) / 256;
  int nb_prep = NPAD * D_DIM / 256;
  int nb_hist = (E + 2047) / 2048;        // 8 edges/thread
  int nb_scat = (E + 255) / 256;
  int gx = (N + 127) / 128;               // 391; gemm tiles = gx*5, scatter role = gx
  int echunk = (E + gx - 1) / gx;         // ~4093 edges per scatter role block

  hipMemsetAsync(cntS, 0, (size_t)NSH * Np * 4, stream);

  setup_fused<<<nb_hist + nb_cvt + nb_prep, 256, 0, stream>>>(
      feat, fb, W_lin, W_res, att_l, att_r, Bt, N * 256, nb_hist, nb_cvt,
      eidx + E, cntS, rank, E, Np);

  scan_partial<<<nb, 256, 0, stream>>>(cntS, bsum, N, Np);
  scan_apply<<<nb, 256, 0, stream>>>(cntS, bsum, row_ptr, soffA, N, Np);

  gemm_scatter<<<gx * 6, 256, 0, stream>>>(
      fb, Bt, out, xbf, alpha_l, alpha_r, N, gx,
      eidx, ew, soffA, rank, pairs, E, Np, echunk, fuse);

  if (!fuse)
    scatter_kernel<<<nb_scat, 256, 0, stream>>>(eidx, ew, soffA, rank, pairs, E, Np);

  agg_kernel<<<(N + 1) / 2, 256, 0, stream>>>(row_ptr, pairs, alpha_l, alpha_r, xbf, out, N);
}